// Round 8
// baseline (7422.456 us; speedup 1.0000x reference)
//
#include <hip/hip_runtime.h>
#include <hip/hip_bf16.h>
#include <hip/hip_fp16.h>
#include <stdint.h>

#define BB 32
#define TT 2048
#define HH 512
#define MM (BB*TT)   // 65536 rows

typedef __attribute__((ext_vector_type(8))) short bf16x8;
typedef __attribute__((ext_vector_type(4))) float f32x4;
typedef __attribute__((ext_vector_type(2))) float f32x2;
typedef __attribute__((ext_vector_type(4))) unsigned short us4;
typedef __attribute__((ext_vector_type(8))) unsigned short us8;
typedef unsigned long long u64;

__device__ __forceinline__ unsigned short f2bf(float f) {
  __hip_bfloat16 h = __float2bfloat16(f);
  return *reinterpret_cast<unsigned short*>(&h);
}
__device__ __forceinline__ float bf2f(unsigned short u) {
  return __uint_as_float(((unsigned int)u) << 16);
}

// lgkm-only workgroup barrier: does NOT drain vmcnt
__device__ __forceinline__ void wg_barrier_lgkm() {
  asm volatile("s_waitcnt lgkmcnt(0)\n\ts_barrier" ::: "memory");
}

// fast sigmoid / tanh (v_exp + v_rcp; |err| ~1e-6)
__device__ __forceinline__ float fast_sigmoid(float x) {
  float e = __expf(-x);
  return __builtin_amdgcn_rcpf(1.f + e);
}
__device__ __forceinline__ float fast_tanh(float x) {
  float xc = fminf(fmaxf(x, -15.f), 15.f);
  float e2 = __expf(2.f * xc);
  return (e2 - 1.f) * __builtin_amdgcn_rcpf(e2 + 1.f);
}

// ---------------------------------------------------------------------------
// Weight convert + transpose: W[k][n] fp32 -> WT[n][k] bf16 (and hi/lo for wc_i)
// ---------------------------------------------------------------------------
__global__ void wconv_kernel(const float* __restrict__ wu, const float* __restrict__ wr,
                             const float* __restrict__ wc,
                             unsigned short* __restrict__ wuT, unsigned short* __restrict__ wrT,
                             unsigned short* __restrict__ wcTh, unsigned short* __restrict__ wcTl) {
  int idx = blockIdx.x * 256 + threadIdx.x;      // 0..262143
  int n = idx >> 9, k = idx & 511;
  int src = k * HH + n;
  wuT[idx] = f2bf(wu[src]);
  wrT[idx] = f2bf(wr[src]);
  float v = wc[src];
  unsigned short hi = f2bf(v);
  wcTh[idx] = hi;
  wcTl[idx] = f2bf(v - bf2f(hi));
}

// ---------------------------------------------------------------------------
// Projection GEMM (unchanged from R5).
// ---------------------------------------------------------------------------
template<int MODE>
__global__ __launch_bounds__(256) void proj_gemm(
    const float* __restrict__ X,
    const unsigned short* __restrict__ B0T,
    const unsigned short* __restrict__ B1T,
    const float* __restrict__ bias0,
    const float* __restrict__ bias1,
    void* __restrict__ outp) {
  __shared__ __attribute__((aligned(16))) unsigned short Ah[128][72];
  __shared__ __attribute__((aligned(16))) unsigned short Al[128][72];
  __shared__ __attribute__((aligned(16))) unsigned short Bs0[64][72];
  __shared__ __attribute__((aligned(16))) unsigned short Bs1[64][72];
  const int tid = threadIdx.x;
  const int w = tid >> 6, l = tid & 63;
  const int lr = l & 15, lk = l >> 4;
  const int rowBase = blockIdx.x * 128;
  const int colBase = blockIdx.y * 64;

  f32x4 acc0[2][4], acc1[2][4];
  const f32x4 zero = {0.f, 0.f, 0.f, 0.f};
  #pragma unroll
  for (int m = 0; m < 2; ++m)
    #pragma unroll
    for (int n = 0; n < 4; ++n) { acc0[m][n] = zero; acc1[m][n] = zero; }

  for (int kt = 0; kt < 8; ++kt) {
    #pragma unroll
    for (int i = 0; i < 8; ++i) {
      int idx = tid + 256 * i;
      int r = idx >> 4, c4 = idx & 15;
      float4 v = *reinterpret_cast<const float4*>(
          X + (size_t)(rowBase + r) * HH + kt * 64 + c4 * 4);
      us4 hv;
      hv.x = f2bf(v.x); hv.y = f2bf(v.y); hv.z = f2bf(v.z); hv.w = f2bf(v.w);
      *reinterpret_cast<us4*>(&Ah[r][c4 * 4]) = hv;
      if (MODE == 1) {
        us4 lv;
        lv.x = f2bf(v.x - bf2f(hv.x)); lv.y = f2bf(v.y - bf2f(hv.y));
        lv.z = f2bf(v.z - bf2f(hv.z)); lv.w = f2bf(v.w - bf2f(hv.w));
        *reinterpret_cast<us4*>(&Al[r][c4 * 4]) = lv;
      }
    }
    #pragma unroll
    for (int i = 0; i < 2; ++i) {
      int idx = tid + 256 * i;
      int n = idx >> 3, k8 = idx & 7;
      const size_t go = (size_t)(colBase + n) * HH + kt * 64 + k8 * 8;
      *reinterpret_cast<us8*>(&Bs0[n][k8 * 8]) = *reinterpret_cast<const us8*>(B0T + go);
      *reinterpret_cast<us8*>(&Bs1[n][k8 * 8]) = *reinterpret_cast<const us8*>(B1T + go);
    }
    __syncthreads();
    #pragma unroll
    for (int ks = 0; ks < 2; ++ks) {
      const int k0 = ks * 32 + lk * 8;
      bf16x8 a[2], b0[4], b1[4];
      #pragma unroll
      for (int m = 0; m < 2; ++m)
        a[m] = *reinterpret_cast<const bf16x8*>(&Ah[32 * w + 16 * m + lr][k0]);
      #pragma unroll
      for (int n = 0; n < 4; ++n) {
        b0[n] = *reinterpret_cast<const bf16x8*>(&Bs0[16 * n + lr][k0]);
        b1[n] = *reinterpret_cast<const bf16x8*>(&Bs1[16 * n + lr][k0]);
      }
      if (MODE == 1) {
        bf16x8 al[2];
        #pragma unroll
        for (int m = 0; m < 2; ++m)
          al[m] = *reinterpret_cast<const bf16x8*>(&Al[32 * w + 16 * m + lr][k0]);
        #pragma unroll
        for (int m = 0; m < 2; ++m)
          #pragma unroll
          for (int n = 0; n < 4; ++n) {
            acc0[m][n] = __builtin_amdgcn_mfma_f32_16x16x32_bf16(a[m],  b0[n], acc0[m][n], 0, 0, 0);
            acc0[m][n] = __builtin_amdgcn_mfma_f32_16x16x32_bf16(a[m],  b1[n], acc0[m][n], 0, 0, 0);
            acc0[m][n] = __builtin_amdgcn_mfma_f32_16x16x32_bf16(al[m], b0[n], acc0[m][n], 0, 0, 0);
          }
      } else {
        #pragma unroll
        for (int m = 0; m < 2; ++m)
          #pragma unroll
          for (int n = 0; n < 4; ++n) {
            acc0[m][n] = __builtin_amdgcn_mfma_f32_16x16x32_bf16(a[m], b0[n], acc0[m][n], 0, 0, 0);
            acc1[m][n] = __builtin_amdgcn_mfma_f32_16x16x32_bf16(a[m], b1[n], acc1[m][n], 0, 0, 0);
          }
      }
    }
    __syncthreads();
  }
  #pragma unroll
  for (int m = 0; m < 2; ++m) {
    #pragma unroll
    for (int n = 0; n < 4; ++n) {
      const int col = colBase + 16 * n + lr;
      const float bv0 = bias0[col];
      const float bv1 = (MODE == 0) ? bias1[col] : 0.f;
      #pragma unroll
      for (int q = 0; q < 4; ++q) {
        const int row = rowBase + 32 * w + 16 * m + lk * 4 + q;
        const size_t o = (size_t)row * HH + col;
        if (MODE == 0) {
          float v0 = acc0[m][n][q] + bv0;
          float v1 = acc1[m][n][q] + bv1;
          unsigned int pk = (unsigned int)__half_as_ushort(__float2half(v0)) |
                            ((unsigned int)__half_as_ushort(__float2half(v1)) << 16);
          reinterpret_cast<unsigned int*>(outp)[o] = pk;
        } else {
          reinterpret_cast<__half*>(outp)[o] = __float2half(acc0[m][n][q] + bv0);
        }
      }
    }
  }
}

// ---------------------------------------------------------------------------
// Persistent scan with a DEDICATED REDUCER WAVE.
// 256 WGs x 576 thr (9 waves). WG (b,g) owns h columns [64g,64g+64).
//
// Waves 0-7 (matvec): their ONLY VMEM ever is the poll load -> the poll's
//   implicit vmcnt(0) waits on nothing else (R5/R7's hidden stall: wave0's
//   proj prefetch + out-store drained at its next poll, putting ~900cy HBM
//   latency on the batch critical path every step).
//   Loop t: [t>0: poll tagged h-words] -> f32x2 matvec -> ds_write parts
//   -> barrier.
// Wave 8 (reducer): barrier -> reduce parts (24 ds_read_b32) -> nonlin ->
//   publish {tag t+1, h} (agent-scope 8B, LLC) -> out[t] -> prefetch proj(t+1).
//   All its global latency hides in the step slack, OFF the chain. It owns
//   all proj reads and out writes for its 64 columns, so the out overwrite
//   of packed proj needs no cross-wave ordering.
// Barrier alignment: matvec iter t ends with barrier instance t+1; wave8
//   iter t STARTS with instance t+1 -> reads parts[t&1] between instances
//   t+1 and t+2; matvec rewrites parts[t&1] at iter t+2, after instance
//   t+2 -> safe. hslow overwrite keeps R5's poll-chain induction (one extra
//   hop through the producer's own matvec waves).
// ---------------------------------------------------------------------------
__global__ __launch_bounds__(576, 2) void scan_kernel(
    const float* __restrict__ wu_h, const float* __restrict__ wr_h,
    const float* __restrict__ wc_h,
    float* __restrict__ out, const __half* __restrict__ cx,
    u64* __restrict__ hslow) {          // [2][BB][HH] of {tag32, h_bits32}
  const int blk = blockIdx.x;
  const int b = (blk & 7) + ((blk >> 6) << 3);   // 8 WGs of a batch share blk%8
  const int g = (blk >> 3) & 7;
  const int tid = threadIdx.x;
  const int w = tid >> 6, l = tid & 63;
  const int j = g * 64 + l;
  const size_t bo = (size_t)b * TT * HH;

  __shared__ float parts[2][8][3][64];

  if (w < 8) {
    // -------- matvec wave: k-slice w, output columns [64g, 64g+64) --------
    f32x2 wu2[32], wr2[32], wc2[32];
    #pragma unroll
    for (int i = 0; i < 32; ++i) {
      const size_t o0 = (size_t)(w * 64 + 2 * i) * HH + j;
      wu2[i] = f32x2{wu_h[o0], wu_h[o0 + HH]};
      wr2[i] = f32x2{wr_h[o0], wr_h[o0 + HH]};
      wc2[i] = f32x2{wc_h[o0], wc_h[o0 + HH]};
    }
    u64* const poll = hslow + (size_t)b * HH + w * 64 + l;

    for (int t = 0; t < TT; ++t) {
      float hval = 0.f;
      if (t > 0) {
        u64 v;
        for (;;) {
          v = __hip_atomic_load(poll + (size_t)(t & 1) * (BB * HH),
                                __ATOMIC_RELAXED, __HIP_MEMORY_SCOPE_AGENT);
          if (__all((int)((unsigned int)(v >> 32) >= (unsigned int)t))) break;
        }
        hval = __uint_as_float((unsigned int)v);
      }
      f32x2 au2 = {0.f, 0.f}, ar2 = {0.f, 0.f}, ac2 = {0.f, 0.f};
      const unsigned int hbits = __float_as_uint(hval);
      #pragma unroll
      for (int i = 0; i < 32; ++i) {
        f32x2 hp;
        hp.x = __uint_as_float(__builtin_amdgcn_readlane(hbits, 2 * i));
        hp.y = __uint_as_float(__builtin_amdgcn_readlane(hbits, 2 * i + 1));
        au2 = __builtin_elementwise_fma(hp, wu2[i], au2);
        ar2 = __builtin_elementwise_fma(hp, wr2[i], ar2);
        ac2 = __builtin_elementwise_fma(hp, wc2[i], ac2);
      }
      const int pb = t & 1;
      parts[pb][w][0][l] = au2.x + au2.y;
      parts[pb][w][1][l] = ar2.x + ar2.y;
      parts[pb][w][2][l] = ac2.x + ac2.y;
      wg_barrier_lgkm();
    }
  } else {
    // -------- reducer wave: owns proj reads, h, publish, out writes --------
    unsigned int* outu = reinterpret_cast<unsigned int*>(out);
    const unsigned short* cxu = reinterpret_cast<const unsigned short*>(cx);
    unsigned int urx_c = outu[bo + j];   // packed {f16 u_x, f16 r_x} for t=0
    unsigned short cx_c = cxu[bo + j];   // f16 c_x for t=0
    float hprev = 0.f;
    u64* const pub = hslow + (size_t)b * HH + j;

    for (int t = 0; t < TT; ++t) {
      wg_barrier_lgkm();
      const int pb = t & 1;
      float su = 0.f, sr = 0.f, sc = 0.f;
      #pragma unroll
      for (int ww = 0; ww < 8; ++ww) {
        su += parts[pb][ww][0][l];
        sr += parts[pb][ww][1][l];
        sc += parts[pb][ww][2][l];
      }
      const float ux = __half2float(__ushort_as_half((unsigned short)(urx_c & 0xffffu)));
      const float rx = __half2float(__ushort_as_half((unsigned short)(urx_c >> 16)));
      const float cxf = __half2float(__ushort_as_half(cx_c));
      const float uu = fast_sigmoid(su + ux);
      const float rr = fast_sigmoid(sr + rx);
      const float ccv = fast_tanh(cxf + rr * sc);
      const float h = hprev + uu * (ccv - hprev);
      hprev = h;
      // publish FIRST (critical path): one 8B tagged agent store
      const u64 pv = ((u64)(unsigned int)(t + 1) << 32) | (u64)__float_as_uint(h);
      __hip_atomic_store(pub + (size_t)((t + 1) & 1) * (BB * HH), pv,
                         __ATOMIC_RELAXED, __HIP_MEMORY_SCOPE_AGENT);
      // off-chain: output store + next-step proj prefetch (full step to land)
      out[bo + (size_t)t * HH + j] = h;
      if (t + 1 < TT) {
        urx_c = outu[bo + (size_t)(t + 1) * HH + j];
        cx_c  = cxu[bo + (size_t)(t + 1) * HH + j];
      }
    }
  }
}

// ---------------------------------------------------------------------------
extern "C" void kernel_launch(void* const* d_in, const int* in_sizes, int n_in,
                              void* d_out, int out_size, void* d_ws, size_t ws_size,
                              hipStream_t stream) {
  const float* x    = (const float*)d_in[0];
  const float* wu_i = (const float*)d_in[1];
  const float* wu_h = (const float*)d_in[2];
  const float* bu   = (const float*)d_in[3];
  const float* wr_i = (const float*)d_in[4];
  const float* wr_h = (const float*)d_in[5];
  const float* br   = (const float*)d_in[6];
  const float* wc_i = (const float*)d_in[7];
  const float* wc_h = (const float*)d_in[8];
  const float* bc   = (const float*)d_in[9];
  float* out = (float*)d_out;

  // ws layout (~66.7 MiB total)
  char* ws = (char*)d_ws;
  __half* cx = (__half*)ws;                                  // 64 MiB c_x f16
  unsigned short* wuT  = (unsigned short*)(ws + (size_t)MM * HH * 2);
  unsigned short* wrT  = wuT + HH * HH;
  unsigned short* wcTh = wrT + HH * HH;
  unsigned short* wcTl = wcTh + HH * HH;
  u64* hslow = (u64*)(wcTl + HH * HH);                       // [2][BB][HH] u64 (512 KiB)

  hipMemsetAsync(hslow, 0, (size_t)2 * BB * HH * sizeof(u64), stream);
  wconv_kernel<<<1024, 256, 0, stream>>>(wu_i, wr_i, wc_i, wuT, wrT, wcTh, wcTl);
  proj_gemm<0><<<dim3(MM / 128, 8), 256, 0, stream>>>(x, wuT, wrT, bu, br, (void*)out);
  proj_gemm<1><<<dim3(MM / 128, 8), 256, 0, stream>>>(x, wcTh, wcTl, bc, bc, (void*)cx);

  void* args[] = { (void*)&wu_h, (void*)&wr_h, (void*)&wc_h, (void*)&out,
                   (void*)&cx, (void*)&hslow };
  hipLaunchCooperativeKernel((void*)scan_kernel, dim3(256), dim3(576), args, 0, stream);
}

// Round 9
// 5023.971 us; speedup vs baseline: 1.4774x; 1.4774x over previous
//
#include <hip/hip_runtime.h>
#include <hip/hip_bf16.h>
#include <hip/hip_fp16.h>
#include <stdint.h>

#define BB 32
#define TT 2048
#define HH 512
#define MM (BB*TT)   // 65536 rows

typedef __attribute__((ext_vector_type(8))) short bf16x8;
typedef __attribute__((ext_vector_type(4))) float f32x4;
typedef __attribute__((ext_vector_type(2))) float f32x2;
typedef __attribute__((ext_vector_type(4))) unsigned short us4;
typedef __attribute__((ext_vector_type(8))) unsigned short us8;
typedef unsigned long long u64;

__device__ __forceinline__ unsigned short f2bf(float f) {
  __hip_bfloat16 h = __float2bfloat16(f);
  return *reinterpret_cast<unsigned short*>(&h);
}
__device__ __forceinline__ float bf2f(unsigned short u) {
  return __uint_as_float(((unsigned int)u) << 16);
}

// lgkm-only workgroup barrier: does NOT drain vmcnt
__device__ __forceinline__ void wg_barrier_lgkm() {
  asm volatile("s_waitcnt lgkmcnt(0)\n\ts_barrier" ::: "memory");
}

// fast sigmoid / tanh (v_exp + v_rcp; |err| ~1e-6)
__device__ __forceinline__ float fast_sigmoid(float x) {
  float e = __expf(-x);
  return __builtin_amdgcn_rcpf(1.f + e);
}
__device__ __forceinline__ float fast_tanh(float x) {
  float xc = fminf(fmaxf(x, -15.f), 15.f);
  float e2 = __expf(2.f * xc);
  return (e2 - 1.f) * __builtin_amdgcn_rcpf(e2 + 1.f);
}

// ---------------------------------------------------------------------------
// Weight convert + transpose: W[k][n] fp32 -> WT[n][k] bf16 (and hi/lo for wc_i)
// ---------------------------------------------------------------------------
__global__ void wconv_kernel(const float* __restrict__ wu, const float* __restrict__ wr,
                             const float* __restrict__ wc,
                             unsigned short* __restrict__ wuT, unsigned short* __restrict__ wrT,
                             unsigned short* __restrict__ wcTh, unsigned short* __restrict__ wcTl) {
  int idx = blockIdx.x * 256 + threadIdx.x;      // 0..262143
  int n = idx >> 9, k = idx & 511;
  int src = k * HH + n;
  wuT[idx] = f2bf(wu[src]);
  wrT[idx] = f2bf(wr[src]);
  float v = wc[src];
  unsigned short hi = f2bf(v);
  wcTh[idx] = hi;
  wcTl[idx] = f2bf(v - bf2f(hi));
}

// ---------------------------------------------------------------------------
// Projection GEMM (unchanged from R5).
// ---------------------------------------------------------------------------
template<int MODE>
__global__ __launch_bounds__(256) void proj_gemm(
    const float* __restrict__ X,
    const unsigned short* __restrict__ B0T,
    const unsigned short* __restrict__ B1T,
    const float* __restrict__ bias0,
    const float* __restrict__ bias1,
    void* __restrict__ outp) {
  __shared__ __attribute__((aligned(16))) unsigned short Ah[128][72];
  __shared__ __attribute__((aligned(16))) unsigned short Al[128][72];
  __shared__ __attribute__((aligned(16))) unsigned short Bs0[64][72];
  __shared__ __attribute__((aligned(16))) unsigned short Bs1[64][72];
  const int tid = threadIdx.x;
  const int w = tid >> 6, l = tid & 63;
  const int lr = l & 15, lk = l >> 4;
  const int rowBase = blockIdx.x * 128;
  const int colBase = blockIdx.y * 64;

  f32x4 acc0[2][4], acc1[2][4];
  const f32x4 zero = {0.f, 0.f, 0.f, 0.f};
  #pragma unroll
  for (int m = 0; m < 2; ++m)
    #pragma unroll
    for (int n = 0; n < 4; ++n) { acc0[m][n] = zero; acc1[m][n] = zero; }

  for (int kt = 0; kt < 8; ++kt) {
    #pragma unroll
    for (int i = 0; i < 8; ++i) {
      int idx = tid + 256 * i;
      int r = idx >> 4, c4 = idx & 15;
      float4 v = *reinterpret_cast<const float4*>(
          X + (size_t)(rowBase + r) * HH + kt * 64 + c4 * 4);
      us4 hv;
      hv.x = f2bf(v.x); hv.y = f2bf(v.y); hv.z = f2bf(v.z); hv.w = f2bf(v.w);
      *reinterpret_cast<us4*>(&Ah[r][c4 * 4]) = hv;
      if (MODE == 1) {
        us4 lv;
        lv.x = f2bf(v.x - bf2f(hv.x)); lv.y = f2bf(v.y - bf2f(hv.y));
        lv.z = f2bf(v.z - bf2f(hv.z)); lv.w = f2bf(v.w - bf2f(hv.w));
        *reinterpret_cast<us4*>(&Al[r][c4 * 4]) = lv;
      }
    }
    #pragma unroll
    for (int i = 0; i < 2; ++i) {
      int idx = tid + 256 * i;
      int n = idx >> 3, k8 = idx & 7;
      const size_t go = (size_t)(colBase + n) * HH + kt * 64 + k8 * 8;
      *reinterpret_cast<us8*>(&Bs0[n][k8 * 8]) = *reinterpret_cast<const us8*>(B0T + go);
      *reinterpret_cast<us8*>(&Bs1[n][k8 * 8]) = *reinterpret_cast<const us8*>(B1T + go);
    }
    __syncthreads();
    #pragma unroll
    for (int ks = 0; ks < 2; ++ks) {
      const int k0 = ks * 32 + lk * 8;
      bf16x8 a[2], b0[4], b1[4];
      #pragma unroll
      for (int m = 0; m < 2; ++m)
        a[m] = *reinterpret_cast<const bf16x8*>(&Ah[32 * w + 16 * m + lr][k0]);
      #pragma unroll
      for (int n = 0; n < 4; ++n) {
        b0[n] = *reinterpret_cast<const bf16x8*>(&Bs0[16 * n + lr][k0]);
        b1[n] = *reinterpret_cast<const bf16x8*>(&Bs1[16 * n + lr][k0]);
      }
      if (MODE == 1) {
        bf16x8 al[2];
        #pragma unroll
        for (int m = 0; m < 2; ++m)
          al[m] = *reinterpret_cast<const bf16x8*>(&Al[32 * w + 16 * m + lr][k0]);
        #pragma unroll
        for (int m = 0; m < 2; ++m)
          #pragma unroll
          for (int n = 0; n < 4; ++n) {
            acc0[m][n] = __builtin_amdgcn_mfma_f32_16x16x32_bf16(a[m],  b0[n], acc0[m][n], 0, 0, 0);
            acc0[m][n] = __builtin_amdgcn_mfma_f32_16x16x32_bf16(a[m],  b1[n], acc0[m][n], 0, 0, 0);
            acc0[m][n] = __builtin_amdgcn_mfma_f32_16x16x32_bf16(al[m], b0[n], acc0[m][n], 0, 0, 0);
          }
      } else {
        #pragma unroll
        for (int m = 0; m < 2; ++m)
          #pragma unroll
          for (int n = 0; n < 4; ++n) {
            acc0[m][n] = __builtin_amdgcn_mfma_f32_16x16x32_bf16(a[m], b0[n], acc0[m][n], 0, 0, 0);
            acc1[m][n] = __builtin_amdgcn_mfma_f32_16x16x32_bf16(a[m], b1[n], acc1[m][n], 0, 0, 0);
          }
      }
    }
    __syncthreads();
  }
  #pragma unroll
  for (int m = 0; m < 2; ++m) {
    #pragma unroll
    for (int n = 0; n < 4; ++n) {
      const int col = colBase + 16 * n + lr;
      const float bv0 = bias0[col];
      const float bv1 = (MODE == 0) ? bias1[col] : 0.f;
      #pragma unroll
      for (int q = 0; q < 4; ++q) {
        const int row = rowBase + 32 * w + 16 * m + lk * 4 + q;
        const size_t o = (size_t)row * HH + col;
        if (MODE == 0) {
          float v0 = acc0[m][n][q] + bv0;
          float v1 = acc1[m][n][q] + bv1;
          unsigned int pk = (unsigned int)__half_as_ushort(__float2half(v0)) |
                            ((unsigned int)__half_as_ushort(__float2half(v1)) << 16);
          reinterpret_cast<unsigned int*>(outp)[o] = pk;
        } else {
          reinterpret_cast<__half*>(outp)[o] = __float2half(acc0[m][n][q] + bv0);
        }
      }
    }
  }
}

// ---------------------------------------------------------------------------
// Persistent scan, TWO-BATCH INTERLEAVE (R5 structure per batch).
// 128 WGs x 512 thr. WG (blk) serves batches bA=(blk&7)+((blk>>6)<<3) and
// bB=bA+16 with the SAME weight registers (weights are batch-independent).
// Per iteration t: [poll A | matvec A | barrier | wave0: reduce+publish A]
// then the same for B. While A's publish propagates through the LLC, the WG
// computes B -- hiding the handoff latency and throttling the spin (first
// poll usually succeeds). R8 lesson applied: the publisher (wave0) is a full
// matvec participant, arrives at the barrier with the others, never parks.
// Wave0's vmcnt contaminators (out-stores + proj prefetches for BOTH batches)
// are batched into the B-tail so the A-chain stays clean.
// parts WAR safety: per-batch parts[2][...] double buffer + the per-half
// barrier (same induction as R5); batches use disjoint arrays.
// ---------------------------------------------------------------------------
__global__ __launch_bounds__(512, 2) void scan_kernel(
    const float* __restrict__ wu_h, const float* __restrict__ wr_h,
    const float* __restrict__ wc_h,
    float* __restrict__ out, const __half* __restrict__ cx,
    u64* __restrict__ hslow) {          // [2][BB][HH] of {tag32, h_bits32}
  const int blk = blockIdx.x;                    // 0..127
  const int bA = (blk & 7) + ((blk >> 6) << 3);  // 0..15 ; 8 WGs share blk%8
  const int bB = bA + 16;
  const int g = (blk >> 3) & 7;
  const int tid = threadIdx.x;
  const int w = tid >> 6, l = tid & 63;
  const int j = g * 64 + l;

  // weights as k-pair float2 (shared by both batches)
  f32x2 wu2[32], wr2[32], wc2[32];
  #pragma unroll
  for (int i = 0; i < 32; ++i) {
    const size_t o0 = (size_t)(w * 64 + 2 * i) * HH + j;
    wu2[i] = f32x2{wu_h[o0], wu_h[o0 + HH]};
    wr2[i] = f32x2{wr_h[o0], wr_h[o0 + HH]};
    wc2[i] = f32x2{wc_h[o0], wc_h[o0 + HH]};
  }

  __shared__ float partsA[2][8][3][64];
  __shared__ float partsB[2][8][3][64];

  unsigned int* outu = reinterpret_cast<unsigned int*>(out);
  const unsigned short* cxu = reinterpret_cast<const unsigned short*>(cx);
  const size_t boA = (size_t)bA * TT * HH;
  const size_t boB = (size_t)bB * TT * HH;

  float hprevA = 0.f, hprevB = 0.f;
  unsigned int urxA = 0, urxB = 0;
  unsigned short cxA = 0, cxB = 0;
  if (w == 0) {
    urxA = outu[boA + j]; cxA = cxu[boA + j];
    urxB = outu[boB + j]; cxB = cxu[boB + j];
  }
  u64* const pollA = hslow + (size_t)bA * HH + w * 64 + l;
  u64* const pubA  = hslow + (size_t)bA * HH + j;
  u64* const pollB = hslow + (size_t)bB * HH + w * 64 + l;
  u64* const pubB  = hslow + (size_t)bB * HH + j;

  for (int t = 0; t < TT; ++t) {
    const int pb = t & 1;
    // ================= half A =================
    {
      float hval = 0.f;
      if (t > 0) {
        u64 v;
        for (;;) {
          v = __hip_atomic_load(pollA + (size_t)pb * (BB * HH),
                                __ATOMIC_RELAXED, __HIP_MEMORY_SCOPE_AGENT);
          if (__all((int)((unsigned int)(v >> 32) >= (unsigned int)t))) break;
          __builtin_amdgcn_s_sleep(1);
        }
        hval = __uint_as_float((unsigned int)v);
      }
      f32x2 au2 = {0.f, 0.f}, ar2 = {0.f, 0.f}, ac2 = {0.f, 0.f};
      const unsigned int hbits = __float_as_uint(hval);
      #pragma unroll
      for (int i = 0; i < 32; ++i) {
        f32x2 hp;
        hp.x = __uint_as_float(__builtin_amdgcn_readlane(hbits, 2 * i));
        hp.y = __uint_as_float(__builtin_amdgcn_readlane(hbits, 2 * i + 1));
        au2 = __builtin_elementwise_fma(hp, wu2[i], au2);
        ar2 = __builtin_elementwise_fma(hp, wr2[i], ar2);
        ac2 = __builtin_elementwise_fma(hp, wc2[i], ac2);
      }
      partsA[pb][w][0][l] = au2.x + au2.y;
      partsA[pb][w][1][l] = ar2.x + ar2.y;
      partsA[pb][w][2][l] = ac2.x + ac2.y;
      wg_barrier_lgkm();
      if (w == 0) {
        float su = 0.f, sr = 0.f, sc = 0.f;
        #pragma unroll
        for (int ww = 0; ww < 8; ++ww) {
          su += partsA[pb][ww][0][l];
          sr += partsA[pb][ww][1][l];
          sc += partsA[pb][ww][2][l];
        }
        const float ux = __half2float(__ushort_as_half((unsigned short)(urxA & 0xffffu)));
        const float rx = __half2float(__ushort_as_half((unsigned short)(urxA >> 16)));
        const float cxf = __half2float(__ushort_as_half(cxA));
        const float uu = fast_sigmoid(su + ux);
        const float rr = fast_sigmoid(sr + rx);
        const float ccv = fast_tanh(cxf + rr * sc);
        const float h = hprevA + uu * (ccv - hprevA);
        hprevA = h;
        // publish ONLY (keep the A-chain clean; deferred ops go to B-tail)
        const u64 pv = ((u64)(unsigned int)(t + 1) << 32) | (u64)__float_as_uint(h);
        __hip_atomic_store(pubA + (size_t)((t + 1) & 1) * (BB * HH), pv,
                           __ATOMIC_RELAXED, __HIP_MEMORY_SCOPE_AGENT);
      }
    }
    // ================= half B =================
    {
      float hval = 0.f;
      if (t > 0) {
        u64 v;
        for (;;) {
          v = __hip_atomic_load(pollB + (size_t)pb * (BB * HH),
                                __ATOMIC_RELAXED, __HIP_MEMORY_SCOPE_AGENT);
          if (__all((int)((unsigned int)(v >> 32) >= (unsigned int)t))) break;
          __builtin_amdgcn_s_sleep(1);
        }
        hval = __uint_as_float((unsigned int)v);
      }
      f32x2 au2 = {0.f, 0.f}, ar2 = {0.f, 0.f}, ac2 = {0.f, 0.f};
      const unsigned int hbits = __float_as_uint(hval);
      #pragma unroll
      for (int i = 0; i < 32; ++i) {
        f32x2 hp;
        hp.x = __uint_as_float(__builtin_amdgcn_readlane(hbits, 2 * i));
        hp.y = __uint_as_float(__builtin_amdgcn_readlane(hbits, 2 * i + 1));
        au2 = __builtin_elementwise_fma(hp, wu2[i], au2);
        ar2 = __builtin_elementwise_fma(hp, wr2[i], ar2);
        ac2 = __builtin_elementwise_fma(hp, wc2[i], ac2);
      }
      partsB[pb][w][0][l] = au2.x + au2.y;
      partsB[pb][w][1][l] = ar2.x + ar2.y;
      partsB[pb][w][2][l] = ac2.x + ac2.y;
      wg_barrier_lgkm();
      if (w == 0) {
        float su = 0.f, sr = 0.f, sc = 0.f;
        #pragma unroll
        for (int ww = 0; ww < 8; ++ww) {
          su += partsB[pb][ww][0][l];
          sr += partsB[pb][ww][1][l];
          sc += partsB[pb][ww][2][l];
        }
        const float ux = __half2float(__ushort_as_half((unsigned short)(urxB & 0xffffu)));
        const float rx = __half2float(__ushort_as_half((unsigned short)(urxB >> 16)));
        const float cxf = __half2float(__ushort_as_half(cxB));
        const float uu = fast_sigmoid(su + ux);
        const float rr = fast_sigmoid(sr + rx);
        const float ccv = fast_tanh(cxf + rr * sc);
        const float h = hprevB + uu * (ccv - hprevB);
        hprevB = h;
        const u64 pv = ((u64)(unsigned int)(t + 1) << 32) | (u64)__float_as_uint(h);
        __hip_atomic_store(pubB + (size_t)((t + 1) & 1) * (BB * HH), pv,
                           __ATOMIC_RELAXED, __HIP_MEMORY_SCOPE_AGENT);
        // deferred, off-chain: out stores + next-step proj prefetch for BOTH
        out[boA + (size_t)t * HH + j] = hprevA;
        out[boB + (size_t)t * HH + j] = hprevB;
        if (t + 1 < TT) {
          urxA = outu[boA + (size_t)(t + 1) * HH + j];
          cxA  = cxu[boA + (size_t)(t + 1) * HH + j];
          urxB = outu[boB + (size_t)(t + 1) * HH + j];
          cxB  = cxu[boB + (size_t)(t + 1) * HH + j];
        }
      }
    }
  }
}

// ---------------------------------------------------------------------------
extern "C" void kernel_launch(void* const* d_in, const int* in_sizes, int n_in,
                              void* d_out, int out_size, void* d_ws, size_t ws_size,
                              hipStream_t stream) {
  const float* x    = (const float*)d_in[0];
  const float* wu_i = (const float*)d_in[1];
  const float* wu_h = (const float*)d_in[2];
  const float* bu   = (const float*)d_in[3];
  const float* wr_i = (const float*)d_in[4];
  const float* wr_h = (const float*)d_in[5];
  const float* br   = (const float*)d_in[6];
  const float* wc_i = (const float*)d_in[7];
  const float* wc_h = (const float*)d_in[8];
  const float* bc   = (const float*)d_in[9];
  float* out = (float*)d_out;

  // ws layout (~66.7 MiB total)
  char* ws = (char*)d_ws;
  __half* cx = (__half*)ws;                                  // 64 MiB c_x f16
  unsigned short* wuT  = (unsigned short*)(ws + (size_t)MM * HH * 2);
  unsigned short* wrT  = wuT + HH * HH;
  unsigned short* wcTh = wrT + HH * HH;
  unsigned short* wcTl = wcTh + HH * HH;
  u64* hslow = (u64*)(wcTl + HH * HH);                       // [2][BB][HH] u64 (512 KiB)

  hipMemsetAsync(hslow, 0, (size_t)2 * BB * HH * sizeof(u64), stream);
  wconv_kernel<<<1024, 256, 0, stream>>>(wu_i, wr_i, wc_i, wuT, wrT, wcTh, wcTl);
  proj_gemm<0><<<dim3(MM / 128, 8), 256, 0, stream>>>(x, wuT, wrT, bu, br, (void*)out);
  proj_gemm<1><<<dim3(MM / 128, 8), 256, 0, stream>>>(x, wcTh, wcTl, bc, bc, (void*)cx);

  void* args[] = { (void*)&wu_h, (void*)&wr_h, (void*)&wc_h, (void*)&out,
                   (void*)&cx, (void*)&hslow };
  hipLaunchCooperativeKernel((void*)scan_kernel, dim3(128), dim3(512), args, 0, stream);
}

// Round 10
// 3713.964 us; speedup vs baseline: 1.9985x; 1.3527x over previous
//
#include <hip/hip_runtime.h>
#include <hip/hip_bf16.h>
#include <hip/hip_fp16.h>
#include <stdint.h>

#define BB 32
#define TT 2048
#define HH 512
#define MM (BB*TT)   // 65536 rows

typedef __attribute__((ext_vector_type(8))) short bf16x8;
typedef __attribute__((ext_vector_type(4))) float f32x4;
typedef __attribute__((ext_vector_type(2))) float f32x2;
typedef __attribute__((ext_vector_type(4))) unsigned short us4;
typedef __attribute__((ext_vector_type(8))) unsigned short us8;
typedef unsigned long long u64;

__device__ __forceinline__ unsigned short f2bf(float f) {
  __hip_bfloat16 h = __float2bfloat16(f);
  return *reinterpret_cast<unsigned short*>(&h);
}
__device__ __forceinline__ float bf2f(unsigned short u) {
  return __uint_as_float(((unsigned int)u) << 16);
}

// lgkm-only workgroup barrier: does NOT drain vmcnt
__device__ __forceinline__ void wg_barrier_lgkm() {
  asm volatile("s_waitcnt lgkmcnt(0)\n\ts_barrier" ::: "memory");
}

// fast sigmoid / tanh (v_exp + v_rcp; |err| ~1e-6)
__device__ __forceinline__ float fast_sigmoid(float x) {
  float e = __expf(-x);
  return __builtin_amdgcn_rcpf(1.f + e);
}
__device__ __forceinline__ float fast_tanh(float x) {
  float xc = fminf(fmaxf(x, -15.f), 15.f);
  float e2 = __expf(2.f * xc);
  return (e2 - 1.f) * __builtin_amdgcn_rcpf(e2 + 1.f);
}

// ---------------------------------------------------------------------------
// Weight convert + transpose: W[k][n] fp32 -> WT[n][k] bf16 (and hi/lo for wc_i)
// ---------------------------------------------------------------------------
__global__ void wconv_kernel(const float* __restrict__ wu, const float* __restrict__ wr,
                             const float* __restrict__ wc,
                             unsigned short* __restrict__ wuT, unsigned short* __restrict__ wrT,
                             unsigned short* __restrict__ wcTh, unsigned short* __restrict__ wcTl) {
  int idx = blockIdx.x * 256 + threadIdx.x;      // 0..262143
  int n = idx >> 9, k = idx & 511;
  int src = k * HH + n;
  wuT[idx] = f2bf(wu[src]);
  wrT[idx] = f2bf(wr[src]);
  float v = wc[src];
  unsigned short hi = f2bf(v);
  wcTh[idx] = hi;
  wcTl[idx] = f2bf(v - bf2f(hi));
}

// ---------------------------------------------------------------------------
// Projection GEMM (unchanged from R5).
// ---------------------------------------------------------------------------
template<int MODE>
__global__ __launch_bounds__(256) void proj_gemm(
    const float* __restrict__ X,
    const unsigned short* __restrict__ B0T,
    const unsigned short* __restrict__ B1T,
    const float* __restrict__ bias0,
    const float* __restrict__ bias1,
    void* __restrict__ outp) {
  __shared__ __attribute__((aligned(16))) unsigned short Ah[128][72];
  __shared__ __attribute__((aligned(16))) unsigned short Al[128][72];
  __shared__ __attribute__((aligned(16))) unsigned short Bs0[64][72];
  __shared__ __attribute__((aligned(16))) unsigned short Bs1[64][72];
  const int tid = threadIdx.x;
  const int w = tid >> 6, l = tid & 63;
  const int lr = l & 15, lk = l >> 4;
  const int rowBase = blockIdx.x * 128;
  const int colBase = blockIdx.y * 64;

  f32x4 acc0[2][4], acc1[2][4];
  const f32x4 zero = {0.f, 0.f, 0.f, 0.f};
  #pragma unroll
  for (int m = 0; m < 2; ++m)
    #pragma unroll
    for (int n = 0; n < 4; ++n) { acc0[m][n] = zero; acc1[m][n] = zero; }

  for (int kt = 0; kt < 8; ++kt) {
    #pragma unroll
    for (int i = 0; i < 8; ++i) {
      int idx = tid + 256 * i;
      int r = idx >> 4, c4 = idx & 15;
      float4 v = *reinterpret_cast<const float4*>(
          X + (size_t)(rowBase + r) * HH + kt * 64 + c4 * 4);
      us4 hv;
      hv.x = f2bf(v.x); hv.y = f2bf(v.y); hv.z = f2bf(v.z); hv.w = f2bf(v.w);
      *reinterpret_cast<us4*>(&Ah[r][c4 * 4]) = hv;
      if (MODE == 1) {
        us4 lv;
        lv.x = f2bf(v.x - bf2f(hv.x)); lv.y = f2bf(v.y - bf2f(hv.y));
        lv.z = f2bf(v.z - bf2f(hv.z)); lv.w = f2bf(v.w - bf2f(hv.w));
        *reinterpret_cast<us4*>(&Al[r][c4 * 4]) = lv;
      }
    }
    #pragma unroll
    for (int i = 0; i < 2; ++i) {
      int idx = tid + 256 * i;
      int n = idx >> 3, k8 = idx & 7;
      const size_t go = (size_t)(colBase + n) * HH + kt * 64 + k8 * 8;
      *reinterpret_cast<us8*>(&Bs0[n][k8 * 8]) = *reinterpret_cast<const us8*>(B0T + go);
      *reinterpret_cast<us8*>(&Bs1[n][k8 * 8]) = *reinterpret_cast<const us8*>(B1T + go);
    }
    __syncthreads();
    #pragma unroll
    for (int ks = 0; ks < 2; ++ks) {
      const int k0 = ks * 32 + lk * 8;
      bf16x8 a[2], b0[4], b1[4];
      #pragma unroll
      for (int m = 0; m < 2; ++m)
        a[m] = *reinterpret_cast<const bf16x8*>(&Ah[32 * w + 16 * m + lr][k0]);
      #pragma unroll
      for (int n = 0; n < 4; ++n) {
        b0[n] = *reinterpret_cast<const bf16x8*>(&Bs0[16 * n + lr][k0]);
        b1[n] = *reinterpret_cast<const bf16x8*>(&Bs1[16 * n + lr][k0]);
      }
      if (MODE == 1) {
        bf16x8 al[2];
        #pragma unroll
        for (int m = 0; m < 2; ++m)
          al[m] = *reinterpret_cast<const bf16x8*>(&Al[32 * w + 16 * m + lr][k0]);
        #pragma unroll
        for (int m = 0; m < 2; ++m)
          #pragma unroll
          for (int n = 0; n < 4; ++n) {
            acc0[m][n] = __builtin_amdgcn_mfma_f32_16x16x32_bf16(a[m],  b0[n], acc0[m][n], 0, 0, 0);
            acc0[m][n] = __builtin_amdgcn_mfma_f32_16x16x32_bf16(a[m],  b1[n], acc0[m][n], 0, 0, 0);
            acc0[m][n] = __builtin_amdgcn_mfma_f32_16x16x32_bf16(al[m], b0[n], acc0[m][n], 0, 0, 0);
          }
      } else {
        #pragma unroll
        for (int m = 0; m < 2; ++m)
          #pragma unroll
          for (int n = 0; n < 4; ++n) {
            acc0[m][n] = __builtin_amdgcn_mfma_f32_16x16x32_bf16(a[m], b0[n], acc0[m][n], 0, 0, 0);
            acc1[m][n] = __builtin_amdgcn_mfma_f32_16x16x32_bf16(a[m], b1[n], acc1[m][n], 0, 0, 0);
          }
      }
    }
    __syncthreads();
  }
  #pragma unroll
  for (int m = 0; m < 2; ++m) {
    #pragma unroll
    for (int n = 0; n < 4; ++n) {
      const int col = colBase + 16 * n + lr;
      const float bv0 = bias0[col];
      const float bv1 = (MODE == 0) ? bias1[col] : 0.f;
      #pragma unroll
      for (int q = 0; q < 4; ++q) {
        const int row = rowBase + 32 * w + 16 * m + lk * 4 + q;
        const size_t o = (size_t)row * HH + col;
        if (MODE == 0) {
          float v0 = acc0[m][n][q] + bv0;
          float v1 = acc1[m][n][q] + bv1;
          unsigned int pk = (unsigned int)__half_as_ushort(__float2half(v0)) |
                            ((unsigned int)__half_as_ushort(__float2half(v1)) << 16);
          reinterpret_cast<unsigned int*>(outp)[o] = pk;
        } else {
          reinterpret_cast<__half*>(outp)[o] = __float2half(acc0[m][n][q] + bv0);
        }
      }
    }
  }
}

// ---------------------------------------------------------------------------
// Persistent scan: R5 structure with CLEAN-PUBLISHER duty assignment.
// 256 WGs x 512 thr. WG (b,g) owns h columns [64g,64g+64).
//
// vmcnt retires IN ORDER -> any VMEM op a wave issues before its poll is
// drained by the poll's vmcnt(0). So:
//  - wave0 (reducer/publisher, the critical wave) issues NO VMEM except the
//    publish store. Its poll drains only the publish ack (~300cy residue).
//  - wave1 prefetches proj(t+1) right after its poll(t) succeeds (a full step
//    before its next poll -> drains free) and stages it to LDS; wave0 reads
//    the staging at its tail (lgkm only). Staging needs no double buffer:
//    wave1 rewrites it at poll(t+1)-success, which happens-after every
//    wave0's publish(t), which is program-after wave0's staging read(t).
//  - out-stores: the g==1 WG's 8 waves write out[t-1][64w+l] from their
//    polled hval (covers all 512 cols), issued right after poll success
//    (~1400cy before their next poll -> ack drains free). Row TT-1 is
//    written post-loop by each WG's wave0 for its own columns.
// Proj overwrite hazard: row t is overwritten at poll-success(t+1); every
// proj(t) read (wave1 prefetch at iter t-1) completed before its ds_write at
// iter t < barrier(t) < publish(t) < poll-success(t+1). Safe.
// Numerics are bit-identical to R5 (same matvec/reduce/nonlin/publish math).
// ---------------------------------------------------------------------------
__global__ __launch_bounds__(512, 2) void scan_kernel(
    const float* __restrict__ wu_h, const float* __restrict__ wr_h,
    const float* __restrict__ wc_h,
    float* __restrict__ out, const __half* __restrict__ cx,
    u64* __restrict__ hslow) {          // [2][BB][HH] of {tag32, h_bits32}
  const int blk = blockIdx.x;
  const int b = (blk & 7) + ((blk >> 6) << 3);   // 8 WGs of a batch share blk%8
  const int g = (blk >> 3) & 7;
  const int tid = threadIdx.x;
  const int w = tid >> 6, l = tid & 63;
  const int jg = g * 64 + l;   // column this WG publishes / stages proj for
  const int jp = w * 64 + l;   // column this wave polls
  const size_t bo = (size_t)b * TT * HH;

  // weights as k-pair float2 (wave w covers k in [64w, 64w+64))
  f32x2 wu2[32], wr2[32], wc2[32];
  #pragma unroll
  for (int i = 0; i < 32; ++i) {
    const size_t o0 = (size_t)(w * 64 + 2 * i) * HH + jg;
    wu2[i] = f32x2{wu_h[o0], wu_h[o0 + HH]};
    wr2[i] = f32x2{wr_h[o0], wr_h[o0 + HH]};
    wc2[i] = f32x2{wc_h[o0], wc_h[o0 + HH]};
  }

  __shared__ float parts[2][8][3][64];
  __shared__ unsigned int  stag_urx[64];
  __shared__ unsigned short stag_cx[64];

  unsigned int* outu = reinterpret_cast<unsigned int*>(out);
  const unsigned short* cxu = reinterpret_cast<const unsigned short*>(cx);

  // wave1: prefetch registers, pre-loaded with proj(0) for wave0's columns
  unsigned int urx_p = 0;
  unsigned short cx_p = 0;
  if (w == 1) {
    urx_p = outu[bo + jg];
    cx_p  = cxu[bo + jg];
  }

  float hprev = 0.f;
  u64* const poll = hslow + (size_t)b * HH + jp;
  u64* const pub  = hslow + (size_t)b * HH + jg;
  const bool out_duty = (g == 1);

  for (int t = 0; t < TT; ++t) {
    float hval = 0.f;
    if (t > 0) {
      u64 v;
      for (;;) {
        v = __hip_atomic_load(poll + (size_t)(t & 1) * (BB * HH),
                              __ATOMIC_RELAXED, __HIP_MEMORY_SCOPE_AGENT);
        if (__all((int)((unsigned int)(v >> 32) >= (unsigned int)t))) break;
      }
      hval = __uint_as_float((unsigned int)v);
      // out-duty WG: store h(t-1) for the polled columns, issued EARLY so the
      // store ack drains long before this wave's next poll.
      if (out_duty)
        out[bo + (size_t)(t - 1) * HH + jp] = hval;
    }
    // wave1: stage proj(t) (prefetched last iteration) to LDS, then issue the
    // proj(t+1) prefetch. Both are a full step away from wave1's next poll.
    if (w == 1) {
      stag_urx[l] = urx_p;
      stag_cx[l]  = cx_p;
      if (t + 1 < TT) {
        urx_p = outu[bo + (size_t)(t + 1) * HH + jg];
        cx_p  = cxu[bo + (size_t)(t + 1) * HH + jg];
      }
    }
    // matvec (identical math to R5)
    f32x2 au2 = {0.f, 0.f}, ar2 = {0.f, 0.f}, ac2 = {0.f, 0.f};
    const unsigned int hbits = __float_as_uint(hval);
    #pragma unroll
    for (int i = 0; i < 32; ++i) {
      f32x2 hp;
      hp.x = __uint_as_float(__builtin_amdgcn_readlane(hbits, 2 * i));
      hp.y = __uint_as_float(__builtin_amdgcn_readlane(hbits, 2 * i + 1));
      au2 = __builtin_elementwise_fma(hp, wu2[i], au2);
      ar2 = __builtin_elementwise_fma(hp, wr2[i], ar2);
      ac2 = __builtin_elementwise_fma(hp, wc2[i], ac2);
    }
    const int pb = t & 1;
    parts[pb][w][0][l] = au2.x + au2.y;
    parts[pb][w][1][l] = ar2.x + ar2.y;
    parts[pb][w][2][l] = ac2.x + ac2.y;
    wg_barrier_lgkm();
    if (w == 0) {
      float su = 0.f, sr = 0.f, sc = 0.f;
      #pragma unroll
      for (int ww = 0; ww < 8; ++ww) {
        su += parts[pb][ww][0][l];
        sr += parts[pb][ww][1][l];
        sc += parts[pb][ww][2][l];
      }
      const unsigned int urx_c = stag_urx[l];
      const unsigned short cx_c = stag_cx[l];
      const float ux = __half2float(__ushort_as_half((unsigned short)(urx_c & 0xffffu)));
      const float rx = __half2float(__ushort_as_half((unsigned short)(urx_c >> 16)));
      const float cxf = __half2float(__ushort_as_half(cx_c));
      const float uu = fast_sigmoid(su + ux);
      const float rr = fast_sigmoid(sr + rx);
      const float ccv = fast_tanh(cxf + rr * sc);
      const float h = hprev + uu * (ccv - hprev);
      hprev = h;
      // the ONLY VMEM wave0 ever issues: the tagged publish
      const u64 pv = ((u64)(unsigned int)(t + 1) << 32) | (u64)__float_as_uint(h);
      __hip_atomic_store(pub + (size_t)((t + 1) & 1) * (BB * HH), pv,
                         __ATOMIC_RELAXED, __HIP_MEMORY_SCOPE_AGENT);
    }
    // no second barrier: double-buffered parts removes the WAR hazard
  }
  // final output row: each WG's wave0 writes its own columns (post-loop, off
  // any critical path)
  if (w == 0)
    out[bo + (size_t)(TT - 1) * HH + jg] = hprev;
}

// ---------------------------------------------------------------------------
extern "C" void kernel_launch(void* const* d_in, const int* in_sizes, int n_in,
                              void* d_out, int out_size, void* d_ws, size_t ws_size,
                              hipStream_t stream) {
  const float* x    = (const float*)d_in[0];
  const float* wu_i = (const float*)d_in[1];
  const float* wu_h = (const float*)d_in[2];
  const float* bu   = (const float*)d_in[3];
  const float* wr_i = (const float*)d_in[4];
  const float* wr_h = (const float*)d_in[5];
  const float* br   = (const float*)d_in[6];
  const float* wc_i = (const float*)d_in[7];
  const float* wc_h = (const float*)d_in[8];
  const float* bc   = (const float*)d_in[9];
  float* out = (float*)d_out;

  // ws layout (~66.7 MiB total)
  char* ws = (char*)d_ws;
  __half* cx = (__half*)ws;                                  // 64 MiB c_x f16
  unsigned short* wuT  = (unsigned short*)(ws + (size_t)MM * HH * 2);
  unsigned short* wrT  = wuT + HH * HH;
  unsigned short* wcTh = wrT + HH * HH;
  unsigned short* wcTl = wcTh + HH * HH;
  u64* hslow = (u64*)(wcTl + HH * HH);                       // [2][BB][HH] u64 (512 KiB)

  hipMemsetAsync(hslow, 0, (size_t)2 * BB * HH * sizeof(u64), stream);
  wconv_kernel<<<1024, 256, 0, stream>>>(wu_i, wr_i, wc_i, wuT, wrT, wcTh, wcTl);
  proj_gemm<0><<<dim3(MM / 128, 8), 256, 0, stream>>>(x, wuT, wrT, bu, br, (void*)out);
  proj_gemm<1><<<dim3(MM / 128, 8), 256, 0, stream>>>(x, wcTh, wcTl, bc, bc, (void*)cx);

  void* args[] = { (void*)&wu_h, (void*)&wr_h, (void*)&wc_h, (void*)&out,
                   (void*)&cx, (void*)&hslow };
  hipLaunchCooperativeKernel((void*)scan_kernel, dim3(256), dim3(512), args, 0, stream);
}